// Round 2
// baseline (94.624 us; speedup 1.0000x reference)
//
#include <hip/hip_runtime.h>
#include <hip/hip_bf16.h>

#define K_DIM   1024
#define N_OUT   256
#define XY_COLS 2304   // 9*256

typedef __bf16 bf16x8 __attribute__((ext_vector_type(8)));
typedef float  f32x4  __attribute__((ext_vector_type(4)));

static __device__ __forceinline__ bf16x8 cvt8(float4 lo, float4 hi) {
    bf16x8 r = { (__bf16)lo.x, (__bf16)lo.y, (__bf16)lo.z, (__bf16)lo.w,
                 (__bf16)hi.x, (__bf16)hi.y, (__bf16)hi.z, (__bf16)hi.w };
    return r;
}

// K1: xy[256][2304] = input @ W^T + b_xy  (fp32 out to workspace)
// LDS-free latency-tolerant design: grid = 4 m-tiles(64) x 72 n-tiles(32),
// n fastest (stride-72 == 0 mod 8 -> all m-copies of a W slab on one XCD L2).
// Block = 4 waves; wave w covers K range [w*256, w*256+256) of the SAME
// 64x32 tile (k-split), loading MFMA frags directly from global (each frag
// load = 16 rows x 128B = 16 full cache lines), cvt fp32->bf16 in regs.
// 8 MFMAs per k-step, 8 k-steps, ONE barrier total (k-split reduce via LDS).
__global__ __launch_bounds__(256) void gemm_xy_kernel(
    const float* __restrict__ A,
    const float* __restrict__ W,
    const float* __restrict__ bias,
    float* __restrict__ xy)
{
    const int t    = threadIdx.x;
    const int lane = t & 63;
    const int w    = t >> 6;          // k-split slice
    const int bid  = blockIdx.x;
    const int m    = bid / 72;
    const int n    = bid - m * 72;
    const int l15  = lane & 15;
    const int quad = lane >> 4;

    const int m0 = m * 64;
    const int n0 = n * 32;

    // per-lane row pointers at this wave's k-origin
    const float* pa[4];
    #pragma unroll
    for (int mi = 0; mi < 4; ++mi)
        pa[mi] = A + (size_t)(m0 + mi * 16 + l15) * K_DIM + w * 256 + quad * 8;
    const float* pb[2];
    #pragma unroll
    for (int nj = 0; nj < 2; ++nj)
        pb[nj] = W + (size_t)(n0 + nj * 16 + l15) * K_DIM + w * 256 + quad * 8;

    f32x4 acc[8];
    #pragma unroll
    for (int i = 0; i < 8; ++i) acc[i] = (f32x4){0.f, 0.f, 0.f, 0.f};

    // software pipeline: fp32 regs for current + next step
    float4 a0[4], a1[4], b0[2], b1[2];
    #pragma unroll
    for (int mi = 0; mi < 4; ++mi) { a0[mi] = *(const float4*)pa[mi]; a1[mi] = *(const float4*)(pa[mi] + 4); }
    #pragma unroll
    for (int nj = 0; nj < 2; ++nj) { b0[nj] = *(const float4*)pb[nj]; b1[nj] = *(const float4*)(pb[nj] + 4); }

    #pragma unroll 1
    for (int s = 0; s < 8; ++s) {
        bf16x8 av[4], bv[2];
        #pragma unroll
        for (int mi = 0; mi < 4; ++mi) av[mi] = cvt8(a0[mi], a1[mi]);
        #pragma unroll
        for (int nj = 0; nj < 2; ++nj) bv[nj] = cvt8(b0[nj], b1[nj]);

        if (s < 7) {   // prefetch next k-step
            const int ko = (s + 1) * 32;
            #pragma unroll
            for (int mi = 0; mi < 4; ++mi) { a0[mi] = *(const float4*)(pa[mi] + ko); a1[mi] = *(const float4*)(pa[mi] + ko + 4); }
            #pragma unroll
            for (int nj = 0; nj < 2; ++nj) { b0[nj] = *(const float4*)(pb[nj] + ko); b1[nj] = *(const float4*)(pb[nj] + ko + 4); }
        }

        #pragma unroll
        for (int mi = 0; mi < 4; ++mi)
            #pragma unroll
            for (int nj = 0; nj < 2; ++nj)
                acc[mi * 2 + nj] = __builtin_amdgcn_mfma_f32_16x16x32_bf16(av[mi], bv[nj], acc[mi * 2 + nj], 0, 0, 0);
    }

    // k-split reduction: all waves dump accs, then 256 threads sum 512 f32x4
    __shared__ __align__(16) f32x4 red[4][8][64];   // 32 KB
    #pragma unroll
    for (int i = 0; i < 8; ++i) red[w][i][lane] = acc[i];
    __syncthreads();

    #pragma unroll
    for (int idx = t; idx < 512; idx += 256) {
        const int tile = idx >> 6;
        const int l    = idx & 63;
        f32x4 s = red[0][tile][l] + red[1][tile][l] + red[2][tile][l] + red[3][tile][l];
        const int mi  = tile >> 1;
        const int nj  = tile & 1;
        const int row = m0 + mi * 16 + (l >> 4) * 4;   // C/D: col=lane&15, row=quad*4+reg
        const int col = n0 + nj * 16 + (l & 15);
        const float bcol = bias[col];
        #pragma unroll
        for (int r = 0; r < 4; ++r)
            xy[(size_t)(row + r) * XY_COLS + col] = s[r] + bcol;
    }
}

// K2: per batch b: S[c][j] = sum_i exp(x_c[i]) * exp(y_c[i^j])
//     out[b][j] = sum_c w_out[c]*log(S[c][j]) + w_out[4]*skip[j] + b_out
// Grid 256 blocks, 512 threads (8 waves). Wave wv -> copy c=wv>>1, i-half h=wv&1.
// Lane jh handles j = 4*jh + jl (jl=0..3). i^j = 4*(ih^jh) + (l^jl):
// one b128 ey gather feeds 16 FMAs; ex read is wave-uniform broadcast.
__global__ __launch_bounds__(512) void softxor_kernel(
    const float* __restrict__ xy,
    const float* __restrict__ w_out,
    const float* __restrict__ b_out,
    float* __restrict__ out)
{
    const int b = blockIdx.x;
    const int t = threadIdx.x;

    __shared__ __align__(16) float ex[4][N_OUT];
    __shared__ __align__(16) float ey[4][N_OUT];
    __shared__ __align__(16) float sk[N_OUT];
    __shared__ __align__(16) float part[8][N_OUT];

    const float* row = xy + (long)b * XY_COLS;

    // load the 2304-col row; exp() the first 2048 (x,y), raw skip
    for (int e4 = t; e4 < XY_COLS / 4; e4 += 512) {
        float4 v = *(const float4*)(row + e4 * 4);
        int e = e4 * 4;
        if (e < 1024) {
            float* d = &ex[e >> 8][e & 255];
            d[0] = __expf(v.x); d[1] = __expf(v.y); d[2] = __expf(v.z); d[3] = __expf(v.w);
        } else if (e < 2048) {
            float* d = &ey[(e >> 8) - 4][e & 255];
            d[0] = __expf(v.x); d[1] = __expf(v.y); d[2] = __expf(v.z); d[3] = __expf(v.w);
        } else {
            float* d = &sk[e - 2048];
            d[0] = v.x; d[1] = v.y; d[2] = v.z; d[3] = v.w;
        }
    }
    __syncthreads();

    const int wv = t >> 6;
    const int c  = wv >> 1;
    const int h  = wv & 1;
    const int jh = t & 63;

    float S0 = 0.f, S1 = 0.f, S2 = 0.f, S3 = 0.f;
    const int ih0 = h * 32;
    #pragma unroll 4
    for (int ih = ih0; ih < ih0 + 32; ++ih) {
        float4 xa = *(const float4*)&ex[c][ih * 4];            // broadcast
        float4 yb = *(const float4*)&ey[c][(ih ^ jh) * 4];     // permuted gather
        S0 += xa.x * yb.x + xa.y * yb.y + xa.z * yb.z + xa.w * yb.w;  // jl=0
        S1 += xa.x * yb.y + xa.y * yb.x + xa.z * yb.w + xa.w * yb.z;  // jl=1
        S2 += xa.x * yb.z + xa.y * yb.w + xa.z * yb.x + xa.w * yb.y;  // jl=2
        S3 += xa.x * yb.w + xa.y * yb.z + xa.z * yb.y + xa.w * yb.x;  // jl=3
    }
    *(float4*)&part[wv][jh * 4] = make_float4(S0, S1, S2, S3);
    __syncthreads();

    if (t < N_OUT) {
        float acc = w_out[4] * sk[t] + b_out[0];
        #pragma unroll
        for (int cc = 0; cc < 4; ++cc) {
            float S = part[2 * cc][t] + part[2 * cc + 1][t];
            acc += w_out[cc] * __logf(S);
        }
        out[b * N_OUT + t] = acc;
    }
}

extern "C" void kernel_launch(void* const* d_in, const int* in_sizes, int n_in,
                              void* d_out, int out_size, void* d_ws, size_t ws_size,
                              hipStream_t stream) {
    const float* input = (const float*)d_in[0];
    const float* W_xy  = (const float*)d_in[1];
    const float* b_xy  = (const float*)d_in[2];
    const float* w_out = (const float*)d_in[3];
    const float* b_out = (const float*)d_in[4];
    float* outp = (float*)d_out;
    float* xy   = (float*)d_ws;   // 256*2304*4 = 2.36 MB

    gemm_xy_kernel<<<288, 256, 0, stream>>>(input, W_xy, b_xy, xy);
    softxor_kernel<<<256, 512, 0, stream>>>(xy, w_out, b_out, outp);
}

// Round 3
// 93.599 us; speedup vs baseline: 1.0109x; 1.0109x over previous
//
#include <hip/hip_runtime.h>
#include <hip/hip_bf16.h>

#define K_DIM   1024
#define N_OUT   256
#define XY_COLS 2304   // 9*256

typedef __bf16 bf16x8 __attribute__((ext_vector_type(8)));
typedef float  f32x4  __attribute__((ext_vector_type(4)));

static __device__ __forceinline__ bf16x8 cvt8(float4 lo, float4 hi) {
    bf16x8 r = { (__bf16)lo.x, (__bf16)lo.y, (__bf16)lo.z, (__bf16)lo.w,
                 (__bf16)hi.x, (__bf16)hi.y, (__bf16)hi.z, (__bf16)hi.w };
    return r;
}

// K1: xy[256][2304] = input @ W^T + b_xy; epilogue writes exp() for the
// 2048 x/y columns (raw for the 256 skip columns) so K2 skips the exps.
// Grid = 8 m-tiles(32) x 72 n-tiles(32) = 576 blocks (2.25 blocks/CU,
// 9 waves/CU for latency hiding). Block = 4 waves; wave w covers K range
// [w*256, w*256+256) of the SAME 32x32 tile (k-split), loading MFMA frags
// directly from global (16 rows x 128B = 16 full cache lines per frag),
// cvt fp32->bf16 in regs. 4 MFMAs/k-step, 8 k-steps, ONE barrier total.
__global__ __launch_bounds__(256) void gemm_xy_kernel(
    const float* __restrict__ A,
    const float* __restrict__ W,
    const float* __restrict__ bias,
    float* __restrict__ xy)
{
    const int t    = threadIdx.x;
    const int lane = t & 63;
    const int w    = t >> 6;          // k-split slice
    const int bid  = blockIdx.x;
    const int m    = bid / 72;
    const int n    = bid - m * 72;
    const int l15  = lane & 15;
    const int quad = lane >> 4;

    const int m0 = m * 32;
    const int n0 = n * 32;

    const float* pa[2];
    #pragma unroll
    for (int mi = 0; mi < 2; ++mi)
        pa[mi] = A + (size_t)(m0 + mi * 16 + l15) * K_DIM + w * 256 + quad * 8;
    const float* pb[2];
    #pragma unroll
    for (int nj = 0; nj < 2; ++nj)
        pb[nj] = W + (size_t)(n0 + nj * 16 + l15) * K_DIM + w * 256 + quad * 8;

    f32x4 acc[4];
    #pragma unroll
    for (int i = 0; i < 4; ++i) acc[i] = (f32x4){0.f, 0.f, 0.f, 0.f};

    float4 a0[2], a1[2], b0[2], b1[2];
    #pragma unroll
    for (int mi = 0; mi < 2; ++mi) { a0[mi] = *(const float4*)pa[mi]; a1[mi] = *(const float4*)(pa[mi] + 4); }
    #pragma unroll
    for (int nj = 0; nj < 2; ++nj) { b0[nj] = *(const float4*)pb[nj]; b1[nj] = *(const float4*)(pb[nj] + 4); }

    #pragma unroll 1
    for (int s = 0; s < 8; ++s) {
        bf16x8 av[2], bv[2];
        #pragma unroll
        for (int mi = 0; mi < 2; ++mi) av[mi] = cvt8(a0[mi], a1[mi]);
        #pragma unroll
        for (int nj = 0; nj < 2; ++nj) bv[nj] = cvt8(b0[nj], b1[nj]);

        if (s < 7) {   // prefetch next k-step
            const int ko = (s + 1) * 32;
            #pragma unroll
            for (int mi = 0; mi < 2; ++mi) { a0[mi] = *(const float4*)(pa[mi] + ko); a1[mi] = *(const float4*)(pa[mi] + ko + 4); }
            #pragma unroll
            for (int nj = 0; nj < 2; ++nj) { b0[nj] = *(const float4*)(pb[nj] + ko); b1[nj] = *(const float4*)(pb[nj] + ko + 4); }
        }

        #pragma unroll
        for (int mi = 0; mi < 2; ++mi)
            #pragma unroll
            for (int nj = 0; nj < 2; ++nj)
                acc[mi * 2 + nj] = __builtin_amdgcn_mfma_f32_16x16x32_bf16(av[mi], bv[nj], acc[mi * 2 + nj], 0, 0, 0);
    }

    // k-split reduction across the 4 waves, then fused bias+exp epilogue
    __shared__ __align__(16) f32x4 red[4][4][64];   // 16 KB
    #pragma unroll
    for (int i = 0; i < 4; ++i) red[w][i][lane] = acc[i];
    __syncthreads();

    const int tile = t >> 6;
    const int l    = t & 63;
    f32x4 s = red[0][tile][l] + red[1][tile][l] + red[2][tile][l] + red[3][tile][l];
    const int mi  = tile >> 1;
    const int nj  = tile & 1;
    const int row = m0 + mi * 16 + (l >> 4) * 4;   // C/D: col=lane&15, row=quad*4+reg
    const int col = n0 + nj * 16 + (l & 15);
    const float bcol = bias[col];
    const bool doexp = col < 2048;                 // x,y columns get exp(); skip stays raw
    #pragma unroll
    for (int r = 0; r < 4; ++r) {
        float v = s[r] + bcol;
        xy[(size_t)(row + r) * XY_COLS + col] = doexp ? __expf(v) : v;
    }
}

// K2: per batch b: S[c][j] = sum_i ex_c[i] * ey_c[i^j]   (already exp'd by K1)
//     out[b][j] = sum_c w_out[c]*log(S[c][j]) + w_out[4]*skip[j] + b_out
// Grid 256 blocks, 512 threads (8 waves). Wave wv -> copy c=wv>>1, i-half h=wv&1.
// Lane jh handles j = 4*jh + jl. i^j = 4*(ih^jh) + (l^jl): one b128 ey gather
// feeds 16 FMAs; ex read is wave-uniform broadcast. Gather is a permutation of
// 64 aligned 16B blocks -> bank-balanced, no conflicts.
__global__ __launch_bounds__(512) void softxor_kernel(
    const float* __restrict__ xy,
    const float* __restrict__ w_out,
    const float* __restrict__ b_out,
    float* __restrict__ out)
{
    const int b = blockIdx.x;
    const int t = threadIdx.x;

    __shared__ __align__(16) float ex[4][N_OUT];
    __shared__ __align__(16) float ey[4][N_OUT];
    __shared__ __align__(16) float sk[N_OUT];
    __shared__ __align__(16) float part[8][N_OUT];

    const float* row = xy + (long)b * XY_COLS;

    for (int e4 = t; e4 < XY_COLS / 4; e4 += 512) {
        float4 v = *(const float4*)(row + e4 * 4);
        int e = e4 * 4;
        float* d;
        if (e < 1024)      d = &ex[e >> 8][e & 255];
        else if (e < 2048) d = &ey[(e >> 8) - 4][e & 255];
        else               d = &sk[e - 2048];
        d[0] = v.x; d[1] = v.y; d[2] = v.z; d[3] = v.w;
    }
    __syncthreads();

    const int wv = t >> 6;
    const int c  = wv >> 1;
    const int h  = wv & 1;
    const int jh = t & 63;

    float S0 = 0.f, S1 = 0.f, S2 = 0.f, S3 = 0.f;
    const int ih0 = h * 32;
    #pragma unroll 4
    for (int ih = ih0; ih < ih0 + 32; ++ih) {
        float4 xa = *(const float4*)&ex[c][ih * 4];            // broadcast
        float4 yb = *(const float4*)&ey[c][(ih ^ jh) * 4];     // permuted gather
        S0 += xa.x * yb.x + xa.y * yb.y + xa.z * yb.z + xa.w * yb.w;  // jl=0
        S1 += xa.x * yb.y + xa.y * yb.x + xa.z * yb.w + xa.w * yb.z;  // jl=1
        S2 += xa.x * yb.z + xa.y * yb.w + xa.z * yb.x + xa.w * yb.y;  // jl=2
        S3 += xa.x * yb.w + xa.y * yb.z + xa.z * yb.y + xa.w * yb.x;  // jl=3
    }
    *(float4*)&part[wv][jh * 4] = make_float4(S0, S1, S2, S3);
    __syncthreads();

    if (t < N_OUT) {
        float acc = w_out[4] * sk[t] + b_out[0];
        #pragma unroll
        for (int cc = 0; cc < 4; ++cc) {
            float S = part[2 * cc][t] + part[2 * cc + 1][t];
            acc += w_out[cc] * __logf(S);
        }
        out[b * N_OUT + t] = acc;
    }
}

extern "C" void kernel_launch(void* const* d_in, const int* in_sizes, int n_in,
                              void* d_out, int out_size, void* d_ws, size_t ws_size,
                              hipStream_t stream) {
    const float* input = (const float*)d_in[0];
    const float* W_xy  = (const float*)d_in[1];
    const float* b_xy  = (const float*)d_in[2];
    const float* w_out = (const float*)d_in[3];
    const float* b_out = (const float*)d_in[4];
    float* outp = (float*)d_out;
    float* xy   = (float*)d_ws;   // 256*2304*4 = 2.36 MB

    gemm_xy_kernel<<<576, 256, 0, stream>>>(input, W_xy, b_xy, xy);
    softxor_kernel<<<256, 512, 0, stream>>>(xy, w_out, b_out, outp);
}